// Round 10
// baseline (116.028 us; speedup 1.0000x reference)
//
#include <hip/hip_runtime.h>
#include <hip/hip_bf16.h>
#include <math.h>

// B=2, S=2048, IN=512, E=512, H=8, D=64, window=256 -> 257-key window.
// f32 in/out. cvt3 -> gemm_qkv (128x128, lds-dma; q scaled 0.125*log2e;
// V written PV-frag-tiled VT3[bh][key/8][d][key%8]) -> attn_mfma (64q tile,
// 8 waves pair-split over key tiles; K staged LDS stride-72; exp2 softmax;
// pair-shared P strips stride-328 aliased over K; PV from VT3 dense; O merged
// via LDS) -> gemm_out (64x128, lds-dma).

typedef __bf16 bf16x8 __attribute__((ext_vector_type(8)));
typedef float f32x4 __attribute__((ext_vector_type(4)));

__device__ __forceinline__ unsigned short f2bf(float f) {
  unsigned u = __float_as_uint(f);
  unsigned r = u + 0x7FFFu + ((u >> 16) & 1u);  // RNE; finite inputs
  return (unsigned short)(r >> 16);
}

// async global->LDS DMA, 16B per lane; lds dest = wave-uniform base + lane*16
__device__ __forceinline__ void ldsdma16(void* lds, const void* g) {
  __builtin_amdgcn_global_load_lds(
      (const __attribute__((address_space(1))) unsigned int*)g,
      (__attribute__((address_space(3))) unsigned int*)lds, 16, 0, 0);
}

// ---------------- f32 -> bf16 conversion (x, qkv_w, o_w) ----------------
__global__ __launch_bounds__(256) void cvt3_kernel(
    const float* __restrict__ s0, unsigned short* __restrict__ d0, int n0,
    const float* __restrict__ s1, unsigned short* __restrict__ d1, int n1,
    const float* __restrict__ s2, unsigned short* __restrict__ d2, int n2) {
  int i4 = blockIdx.x * 256 + threadIdx.x;
  const int c0 = n0 >> 2, c1 = (n0 + n1) >> 2, c2 = (n0 + n1 + n2) >> 2;
  const float* s; unsigned short* d; int base4;
  if (i4 < c0)      { s = s0; d = d0; base4 = i4; }
  else if (i4 < c1) { s = s1; d = d1; base4 = i4 - c0; }
  else if (i4 < c2) { s = s2; d = d2; base4 = i4 - c1; }
  else return;
  float4 v = ((const float4*)s)[base4];
  ushort4 o;
  o.x = f2bf(v.x); o.y = f2bf(v.y); o.z = f2bf(v.z); o.w = f2bf(v.w);
  ((ushort4*)d)[base4] = o;
}

// ---------------- QKV projection GEMM (128x128 tile, lds-dma) ----------------
__global__ __launch_bounds__(256) void gemm_qkv(
    const __hip_bfloat16* __restrict__ A, const __hip_bfloat16* __restrict__ Bw,
    const float* __restrict__ bias,
    __hip_bfloat16* __restrict__ qp, __hip_bfloat16* __restrict__ kpb,
    unsigned short* __restrict__ vtb) {
  __shared__ __hip_bfloat16 As[128 * 32];
  __shared__ __hip_bfloat16 Bs[128 * 32];

  const int tid = threadIdx.x, wave = tid >> 6, lane = tid & 63;
  const int m0 = blockIdx.x * 128, n0 = blockIdx.y * 128;
  const int wm = (wave >> 1) * 64, wn = (wave & 1) * 64;
  const int cl = lane & 15, ko = (lane >> 4) * 8;
  const int srow = wave * 16 + (lane >> 2);
  const int scol = (lane & 3) * 8;

  f32x4 acc[4][4] = {};

  for (int k0 = 0; k0 < 512; k0 += 32) {
    __syncthreads();
    ldsdma16(&As[wave * 512],        A  + (size_t)(m0 + srow) * 512 + k0 + scol);
    ldsdma16(&As[2048 + wave * 512], A  + (size_t)(m0 + 64 + srow) * 512 + k0 + scol);
    ldsdma16(&Bs[wave * 512],        Bw + (size_t)(n0 + srow) * 512 + k0 + scol);
    ldsdma16(&Bs[2048 + wave * 512], Bw + (size_t)(n0 + 64 + srow) * 512 + k0 + scol);
    __syncthreads();

    bf16x8 af[4], bf[4];
#pragma unroll
    for (int i = 0; i < 4; i++)
      af[i] = *(const bf16x8*)(&As[(wm + cl + i * 16) * 32 + ko]);
#pragma unroll
    for (int i = 0; i < 4; i++)
      bf[i] = *(const bf16x8*)(&Bs[(wn + cl + i * 16) * 32 + ko]);
#pragma unroll
    for (int mi = 0; mi < 4; mi++)
#pragma unroll
      for (int ni = 0; ni < 4; ni++)
        acc[mi][ni] = __builtin_amdgcn_mfma_f32_16x16x32_bf16(
            af[mi], bf[ni], acc[mi][ni], 0, 0, 0);
  }

  const int crow = (lane >> 4) * 4;
#pragma unroll
  for (int mi = 0; mi < 4; mi++) {
    const int mb = m0 + wm + mi * 16 + crow;
    const int bq = mb >> 11, sl = mb & 2047;  // keys sl..sl+3, sl%4==0
#pragma unroll
    for (int ni = 0; ni < 4; ni++) {
      const int n = n0 + wn + ni * 16 + cl;
      const int h = n / 192;
      const int rem = n - h * 192;
      const int cat = rem >> 6;  // 0=q 1=k 2=v (uniform per 16-col group)
      const int d = rem & 63;
      const float bv = bias[n];
      const size_t bh = (size_t)bq * 8 + h;
      if (cat == 2) {
        ushort4 o;
        o.x = f2bf(acc[mi][ni][0] + bv);
        o.y = f2bf(acc[mi][ni][1] + bv);
        o.z = f2bf(acc[mi][ni][2] + bv);
        o.w = f2bf(acc[mi][ni][3] + bv);
        *(ushort4*)(vtb + bh * 131072 + (sl >> 3) * 512 + d * 8 + (sl & 7)) = o;
      } else {
        __hip_bfloat16* dst = (cat == 0) ? qp : kpb;
        const float sc = (cat == 0) ? 0.18033688011112042f : 1.0f;
#pragma unroll
        for (int r = 0; r < 4; r++)
          dst[(bh * 2048 + sl + r) * 64 + d] =
              __float2bfloat16((acc[mi][ni][r] + bv) * sc);
      }
    }
  }
}

// ---------------- MFMA sliding-window attention (8-wave pair-split) --------
// block = (b,h, 64-query tile), 512 threads. Wave-pair p owns q-rows
// [p*16,p*16+16); key tiles p..p+16 split: parity0 -> tiles p+0..p+8,
// parity1 -> tiles p+9..p+16 (+zero pad tile). Merges via LDS.
__global__ __launch_bounds__(512) void attn_mfma(
    const __hip_bfloat16* __restrict__ qp, const __hip_bfloat16* __restrict__ kp,
    const __hip_bfloat16* __restrict__ vt, const int* __restrict__ pm,
    __hip_bfloat16* __restrict__ vals) {
  __shared__ __hip_bfloat16 sKP[320 * 72];  // K (46KB); later P strips / O merge
  __shared__ float sCM[320];                // pm/range addend: 0 or -3e38
  __shared__ float sMrow[4][2][16];         // per-pair per-parity row max
  __shared__ float sLsum[4][2][16];         // per-pair per-parity row sum

  const int tid = threadIdx.x, wave = tid >> 6, lane = tid & 63;
  const int pair = wave >> 1, parity = wave & 1;
  const int bid = blockIdx.x;
  const int s0 = (bid & 31) * 64;
  const int bh = bid >> 5;
  const int b = bh >> 3, h = bh & 7;
  const int t0 = s0 - 128;
  const int cl = lane & 15;
  const int g4 = (lane >> 4) * 4;   // C-layout row base
  const int ko = (lane >> 4) * 8;   // A/B-frag k offset

  // stage K tile: 320 rows x 128B, 8 threads/row x 16B, 512 threads -> 5 sweeps
  {
    const int e = (tid & 7) * 8;
#pragma unroll
    for (int i = 0; i < 5; i++) {
      int row = (tid >> 3) + i * 64;
      int t = t0 + row; t = min(max(t, 0), 2047);
      *(uint4*)(&sKP[row * 72 + e]) =
          *(const uint4*)(kp + ((size_t)bh * 2048 + t) * 64 + e);
    }
  }
  for (int c = tid; c < 320; c += 512) {
    int t = t0 + c;
    bool ok = (t >= 0 && t < 2048) && (pm[b * 2048 + t] != 0);
    sCM[c] = ok ? 0.0f : -3.0e38f;
  }
  __syncthreads();  // B1: K + sCM ready

  // Q A-frags (both waves of a pair load the same 16 rows)
  const __hip_bfloat16* qrow =
      qp + ((size_t)bh * 2048 + s0 + pair * 16 + cl) * 64 + ko;
  bf16x8 aq0 = *(const bf16x8*)(qrow);
  bf16x8 aq1 = *(const bf16x8*)(qrow + 32);

  // QK^T: parity0 tiles j=0..8 (t=pair+j), parity1 j=0..7 (t=pair+9+j)
  const int nt = 9 - parity;        // wave-uniform
  const int tbase = pair + parity * 9;
  f32x4 acc[9] = {};
#pragma unroll
  for (int j = 0; j < 9; j++) {
    if (j < nt) {
      const int krow = (tbase + j) * 16 + cl;
      bf16x8 b0 = *(const bf16x8*)(&sKP[krow * 72 + ko]);
      bf16x8 b1 = *(const bf16x8*)(&sKP[krow * 72 + ko + 32]);
      f32x4 z = {};
      z = __builtin_amdgcn_mfma_f32_16x16x32_bf16(aq0, b0, z, 0, 0, 0);
      acc[j] = __builtin_amdgcn_mfma_f32_16x16x32_bf16(aq1, b1, z, 0, 0, 0);
    }
  }

  // mask + partial row max
  float mrow[4] = {-3.0e38f, -3.0e38f, -3.0e38f, -3.0e38f};
#pragma unroll
  for (int j = 0; j < 9; j++) {
    if (j < nt) {
      const float ca = sCM[(tbase + j) * 16 + cl];
#pragma unroll
      for (int r = 0; r < 4; r++) {
        float sv = acc[j][r] + ca;
        if (parity == 0 && j == 0) {          // t = pair: dlt may be < 0
          if (cl < g4 + r) sv = -3.0e38f;
        } else if (parity == 1 && j == 7) {   // t = pair+16: dlt may be > 256
          if (cl > g4 + r) sv = -3.0e38f;
        }
        acc[j][r] = sv;
        mrow[r] = fmaxf(mrow[r], sv);
      }
    }
  }
#pragma unroll
  for (int r = 0; r < 4; r++)
#pragma unroll
    for (int off = 1; off < 16; off <<= 1)
      mrow[r] = fmaxf(mrow[r], __shfl_xor(mrow[r], off));
  if (cl == 0) {
#pragma unroll
    for (int r = 0; r < 4; r++) sMrow[pair][parity][g4 + r] = mrow[r];
  }
  __syncthreads();  // B2: partial maxes visible; all K reads done

  float mr[4];
#pragma unroll
  for (int r = 0; r < 4; r++)
    mr[r] = fmaxf(sMrow[pair][0][g4 + r], sMrow[pair][1][g4 + r]);

  float lsum[4] = {0.f, 0.f, 0.f, 0.f};
#pragma unroll
  for (int j = 0; j < 9; j++) {
    if (j < nt) {
#pragma unroll
      for (int r = 0; r < 4; r++) {
        float pv = exp2f(acc[j][r] - mr[r]);  // masked -> exact 0
        acc[j][r] = pv;
        lsum[r] += pv;
      }
    }
  }
#pragma unroll
  for (int r = 0; r < 4; r++)
#pragma unroll
    for (int off = 1; off < 16; off <<= 1)
      lsum[r] += __shfl_xor(lsum[r], off);
  if (cl == 0) {
#pragma unroll
    for (int r = 0; r < 4; r++) sLsum[pair][parity][g4 + r] = lsum[r];
  }

  // write P into the pair-shared strip (aliased over dead K). abs-col indexing.
  __hip_bfloat16* sp = sKP + pair * 5248;  // 16 x 328
#pragma unroll
  for (int j = 0; j < 9; j++) {
    if (j < nt) {
      const int c = (tbase + j) * 16 + cl;
#pragma unroll
      for (int r = 0; r < 4; r++)
        sp[(g4 + r) * 328 + c] = __float2bfloat16(acc[j][r]);
    }
  }
  if (parity == 1) {  // zero the extra tile the 32-aligned PV k-steps touch
    const int zt = (pair & 1) ? (pair - 1) : (pair + 17);
    const int zc = zt * 16 + cl;
#pragma unroll
    for (int r = 0; r < 4; r++)
      sp[(g4 + r) * 328 + zc] = __float2bfloat16(0.f);
  }
  __syncthreads();  // B3: P strips complete, lsum partials visible

  // PV: 9 k-steps of 32 keys split: parity0 ks 0..4, parity1 ks 5..8
  f32x4 oacc[4] = {};
  const int k0p = pair >> 1;
  const int klo = parity ? 5 : 0, khi = parity ? 9 : 5;
  const __hip_bfloat16* vbase = vt + (size_t)bh * 131072;
#pragma unroll
  for (int ks = 0; ks < 9; ks++) {
    if (ks >= klo && ks < khi) {
      const int kk = (k0p + ks) * 32 + ko;   // abs key col, %8==0
      bf16x8 pa = *(const bf16x8*)(&sp[cl * 328 + kk]);
      int tv = t0 + kk; tv = min(max(tv, 0), 2040);
      const __hip_bfloat16* vrow = vbase + (tv >> 3) * 512;
#pragma unroll
      for (int ni = 0; ni < 4; ni++) {
        const int d = ni * 16 + cl;
        bf16x8 vb = *(const bf16x8*)(vrow + d * 8);
        oacc[ni] = __builtin_amdgcn_mfma_f32_16x16x32_bf16(pa, vb, oacc[ni], 0, 0, 0);
      }
    }
  }
  __syncthreads();  // B4: PV done, P region dead

  // merge O: parity1 writes partials (stride-65 padded rows), parity0 combines
  float* sO = (float*)sKP;  // [pair][16][65] f32 = 16.6KB, aliased
  if (parity == 1) {
#pragma unroll
    for (int r = 0; r < 4; r++)
#pragma unroll
      for (int ni = 0; ni < 4; ni++)
        sO[pair * 1040 + (g4 + r) * 65 + ni * 16 + cl] = oacc[ni][r];
  }
  __syncthreads();  // B5

  if (parity == 0) {
#pragma unroll
    for (int r = 0; r < 4; r++) {
      const float lt = lsum[r] + sLsum[pair][1][g4 + r];
      float linv = 1.0f / fmaxf(lt, 1e-20f);
      const int qr = pair * 16 + g4 + r;
      if (sCM[qr + 128] != 0.0f) linv = 0.0f;  // fully-masked query -> 0
      const size_t obase = ((size_t)(b * 2048 + s0 + qr)) * 512 + h * 64 + cl;
#pragma unroll
      for (int ni = 0; ni < 4; ni++) {
        float o = oacc[ni][r] + sO[pair * 1040 + (g4 + r) * 65 + ni * 16 + cl];
        vals[obase + ni * 16] = __float2bfloat16(o * linv);
      }
    }
  }
}

// ---------------- output projection GEMM (64x128 tile, lds-dma, f32 out) ----
__global__ __launch_bounds__(256) void gemm_out(
    const __hip_bfloat16* __restrict__ A, const __hip_bfloat16* __restrict__ Bw,
    const float* __restrict__ bias, float* __restrict__ C) {
  __shared__ __hip_bfloat16 As[64 * 32];
  __shared__ __hip_bfloat16 Bs[128 * 32];

  const int tid = threadIdx.x, wave = tid >> 6, lane = tid & 63;
  const int m0 = blockIdx.x * 64, n0 = blockIdx.y * 128;
  const int wm = (wave >> 1) * 32, wn = (wave & 1) * 64;
  const int cl = lane & 15, ko = (lane >> 4) * 8;
  const int srow = wave * 16 + (lane >> 2);
  const int scol = (lane & 3) * 8;

  f32x4 acc[2][4] = {};

  for (int k0 = 0; k0 < 512; k0 += 32) {
    __syncthreads();
    ldsdma16(&As[wave * 512],        A  + (size_t)(m0 + srow) * 512 + k0 + scol);
    ldsdma16(&Bs[wave * 512],        Bw + (size_t)(n0 + srow) * 512 + k0 + scol);
    ldsdma16(&Bs[2048 + wave * 512], Bw + (size_t)(n0 + 64 + srow) * 512 + k0 + scol);
    __syncthreads();

    bf16x8 af[2], bf[4];
#pragma unroll
    for (int i = 0; i < 2; i++)
      af[i] = *(const bf16x8*)(&As[(wm + cl + i * 16) * 32 + ko]);
#pragma unroll
    for (int i = 0; i < 4; i++)
      bf[i] = *(const bf16x8*)(&Bs[(wn + cl + i * 16) * 32 + ko]);
#pragma unroll
    for (int mi = 0; mi < 2; mi++)
#pragma unroll
      for (int ni = 0; ni < 4; ni++)
        acc[mi][ni] = __builtin_amdgcn_mfma_f32_16x16x32_bf16(
            af[mi], bf[ni], acc[mi][ni], 0, 0, 0);
  }

  const int crow = (lane >> 4) * 4;
#pragma unroll
  for (int mi = 0; mi < 2; mi++) {
#pragma unroll
    for (int ni = 0; ni < 4; ni++) {
      const int n = n0 + wn + ni * 16 + cl;
      const float bv = bias[n];
      const int mb = m0 + wm + mi * 16 + crow;
#pragma unroll
      for (int r = 0; r < 4; r++)
        C[(size_t)(mb + r) * 512 + n] = acc[mi][ni][r] + bv;
    }
  }
}

extern "C" void kernel_launch(void* const* d_in, const int* in_sizes, int n_in,
                              void* d_out, int out_size, void* d_ws, size_t ws_size,
                              hipStream_t stream) {
  const float* x     = (const float*)d_in[0];   // (2,2048,512)
  const int*   pm    = (const int*)d_in[1];     // (2,2048)
  const float* qkv_w = (const float*)d_in[2];   // (1536,512)
  const float* qkv_b = (const float*)d_in[3];   // (1536,)
  const float* o_w   = (const float*)d_in[4];   // (512,512)
  const float* o_b   = (const float*)d_in[5];   // (512,)
  float* out = (float*)d_out;                   // (2,2048,512)

  __hip_bfloat16* wsb   = (__hip_bfloat16*)d_ws;
  __hip_bfloat16* xb    = wsb;               // 2097152
  __hip_bfloat16* wqkvb = wsb + 2097152;     // 786432
  __hip_bfloat16* wob   = wsb + 2883584;     // 262144
  __hip_bfloat16* qp    = wsb + 3145728;     // 2097152  [bh][s][64] (scaled)
  __hip_bfloat16* kp    = wsb + 5242880;     // 2097152  [bh][s][64]
  __hip_bfloat16* vt    = wsb + 7340032;     // 2097152  VT3[bh][k/8][d][k%8]
  __hip_bfloat16* vals  = wsb + 9437184;     // 2097152  [s][512]

  dim3 blk(256);
  cvt3_kernel<<<dim3(3072), blk, 0, stream>>>(
      x, (unsigned short*)xb, 2097152,
      qkv_w, (unsigned short*)wqkvb, 786432,
      o_w, (unsigned short*)wob, 262144);
  gemm_qkv<<<dim3(32, 12), blk, 0, stream>>>(
      xb, wqkvb, qkv_b, qp, kp, (unsigned short*)vt);
  attn_mfma<<<dim3(512), dim3(512), 0, stream>>>(qp, kp, vt, pm, vals);
  gemm_out<<<dim3(64, 4), blk, 0, stream>>>(vals, wob, o_b, out);
}

// Round 11
// 115.158 us; speedup vs baseline: 1.0075x; 1.0075x over previous
//
#include <hip/hip_runtime.h>
#include <hip/hip_bf16.h>
#include <math.h>

// FINAL (R9 config, best measured 115.6 us).
// B=2, S=2048, IN=512, E=512, H=8, D=64, window=256 -> 257-key window.
// f32 in/out. cvt3 -> gemm_qkv (128x128, lds-dma; q scaled 0.125*log2e;
// V written PV-frag-tiled VT3[bh][key/8][d][key%8]) -> attn_mfma (64q tile;
// K staged LDS stride-72; exp2 softmax; P strips stride-328 (conflict-free)
// aliased over K; PV from VT3 dense) -> gemm_out (64x128, lds-dma).

typedef __bf16 bf16x8 __attribute__((ext_vector_type(8)));
typedef float f32x4 __attribute__((ext_vector_type(4)));

__device__ __forceinline__ unsigned short f2bf(float f) {
  unsigned u = __float_as_uint(f);
  unsigned r = u + 0x7FFFu + ((u >> 16) & 1u);  // RNE; finite inputs
  return (unsigned short)(r >> 16);
}

// async global->LDS DMA, 16B per lane; lds dest = wave-uniform base + lane*16
__device__ __forceinline__ void ldsdma16(void* lds, const void* g) {
  __builtin_amdgcn_global_load_lds(
      (const __attribute__((address_space(1))) unsigned int*)g,
      (__attribute__((address_space(3))) unsigned int*)lds, 16, 0, 0);
}

// ---------------- f32 -> bf16 conversion (x, qkv_w, o_w) ----------------
__global__ __launch_bounds__(256) void cvt3_kernel(
    const float* __restrict__ s0, unsigned short* __restrict__ d0, int n0,
    const float* __restrict__ s1, unsigned short* __restrict__ d1, int n1,
    const float* __restrict__ s2, unsigned short* __restrict__ d2, int n2) {
  int i4 = blockIdx.x * 256 + threadIdx.x;
  const int c0 = n0 >> 2, c1 = (n0 + n1) >> 2, c2 = (n0 + n1 + n2) >> 2;
  const float* s; unsigned short* d; int base4;
  if (i4 < c0)      { s = s0; d = d0; base4 = i4; }
  else if (i4 < c1) { s = s1; d = d1; base4 = i4 - c0; }
  else if (i4 < c2) { s = s2; d = d2; base4 = i4 - c1; }
  else return;
  float4 v = ((const float4*)s)[base4];
  ushort4 o;
  o.x = f2bf(v.x); o.y = f2bf(v.y); o.z = f2bf(v.z); o.w = f2bf(v.w);
  ((ushort4*)d)[base4] = o;
}

// ---------------- QKV projection GEMM (128x128 tile, lds-dma) ----------------
// A(4096,512) @ Bw(1536,512)^T + bias -> qp (q*0.125*log2e), kp, vt (VT3 tiled)
__global__ __launch_bounds__(256) void gemm_qkv(
    const __hip_bfloat16* __restrict__ A, const __hip_bfloat16* __restrict__ Bw,
    const float* __restrict__ bias,
    __hip_bfloat16* __restrict__ qp, __hip_bfloat16* __restrict__ kpb,
    unsigned short* __restrict__ vtb) {
  __shared__ __hip_bfloat16 As[128 * 32];  // 64B/row, contiguous (dma layout)
  __shared__ __hip_bfloat16 Bs[128 * 32];

  const int tid = threadIdx.x, wave = tid >> 6, lane = tid & 63;
  const int m0 = blockIdx.x * 128, n0 = blockIdx.y * 128;
  const int wm = (wave >> 1) * 64, wn = (wave & 1) * 64;
  const int cl = lane & 15, ko = (lane >> 4) * 8;
  const int srow = wave * 16 + (lane >> 2);  // dma source row
  const int scol = (lane & 3) * 8;           // dma source k-offset

  f32x4 acc[4][4] = {};

  for (int k0 = 0; k0 < 512; k0 += 32) {
    __syncthreads();  // prev iter frag reads done
    ldsdma16(&As[wave * 512],        A  + (size_t)(m0 + srow) * 512 + k0 + scol);
    ldsdma16(&As[2048 + wave * 512], A  + (size_t)(m0 + 64 + srow) * 512 + k0 + scol);
    ldsdma16(&Bs[wave * 512],        Bw + (size_t)(n0 + srow) * 512 + k0 + scol);
    ldsdma16(&Bs[2048 + wave * 512], Bw + (size_t)(n0 + 64 + srow) * 512 + k0 + scol);
    __syncthreads();  // vmcnt(0) drain + barrier -> LDS ready

    bf16x8 af[4], bf[4];
#pragma unroll
    for (int i = 0; i < 4; i++)
      af[i] = *(const bf16x8*)(&As[(wm + cl + i * 16) * 32 + ko]);
#pragma unroll
    for (int i = 0; i < 4; i++)
      bf[i] = *(const bf16x8*)(&Bs[(wn + cl + i * 16) * 32 + ko]);
#pragma unroll
    for (int mi = 0; mi < 4; mi++)
#pragma unroll
      for (int ni = 0; ni < 4; ni++)
        acc[mi][ni] = __builtin_amdgcn_mfma_f32_16x16x32_bf16(
            af[mi], bf[ni], acc[mi][ni], 0, 0, 0);
  }

  const int crow = (lane >> 4) * 4;
#pragma unroll
  for (int mi = 0; mi < 4; mi++) {
    const int mb = m0 + wm + mi * 16 + crow;
    const int bq = mb >> 11, sl = mb & 2047;  // keys sl..sl+3, sl%4==0
#pragma unroll
    for (int ni = 0; ni < 4; ni++) {
      const int n = n0 + wn + ni * 16 + cl;
      const int h = n / 192;
      const int rem = n - h * 192;
      const int cat = rem >> 6;  // 0=q 1=k 2=v (uniform per 16-col group)
      const int d = rem & 63;
      const float bv = bias[n];
      const size_t bh = (size_t)bq * 8 + h;
      if (cat == 2) {
        ushort4 o;
        o.x = f2bf(acc[mi][ni][0] + bv);
        o.y = f2bf(acc[mi][ni][1] + bv);
        o.z = f2bf(acc[mi][ni][2] + bv);
        o.w = f2bf(acc[mi][ni][3] + bv);
        // VT3[bh][key/8][d][key%8]; keys sl..sl+3 share kb8 (sl%8 in {0,4})
        *(ushort4*)(vtb + bh * 131072 + (sl >> 3) * 512 + d * 8 + (sl & 7)) = o;
      } else {
        __hip_bfloat16* dst = (cat == 0) ? qp : kpb;
        // q: 1/sqrt(64) * log2(e) -> scores directly in exp2 domain
        const float sc = (cat == 0) ? 0.18033688011112042f : 1.0f;
#pragma unroll
        for (int r = 0; r < 4; r++)
          dst[(bh * 2048 + sl + r) * 64 + d] =
              __float2bfloat16((acc[mi][ni][r] + bv) * sc);
      }
    }
  }
}

// ---------------- MFMA sliding-window attention ----------------
// block = (b,h, 64-query tile). Keys span [s0-128, s0+191] = 320 slots.
// Wave w owns q-rows [w*16, w*16+16): key tiles w..w+16. K staged to LDS
// (stride 72). After QK^T + softmax, P strips (per-wave 16x328, stride 328 =
// dword-stride 82 = conflict-free 2-way) alias the dead K region. PV B-frags
// from VT3 (dense 16B/lane). 2 barriers.
__global__ __launch_bounds__(256) void attn_mfma(
    const __hip_bfloat16* __restrict__ qp, const __hip_bfloat16* __restrict__ kp,
    const __hip_bfloat16* __restrict__ vt, const int* __restrict__ pm,
    __hip_bfloat16* __restrict__ vals) {
  __shared__ __hip_bfloat16 sKP[320 * 72];  // K tile (46KB); P strips alias (42KB)
  __shared__ float sCM[320];                // pm/range addend: 0 or -3e38

  const int tid = threadIdx.x, wave = tid >> 6, lane = tid & 63;
  const int bid = blockIdx.x;
  const int s0 = (bid & 31) * 64;
  const int bh = bid >> 5;
  const int b = bh >> 3, h = bh & 7;
  const int t0 = s0 - 128;
  const int cl = lane & 15;
  const int g4 = (lane >> 4) * 4;   // C-layout row base
  const int ko = (lane >> 4) * 8;   // A/B-frag k offset

  // stage K tile: 320 rows x 128B, 8 threads/row x 16B, coalesced
  {
    const int e = (tid & 7) * 8;
#pragma unroll
    for (int i = 0; i < 10; i++) {
      int row = (tid >> 3) + i * 32;
      int t = t0 + row; t = min(max(t, 0), 2047);
      *(uint4*)(&sKP[row * 72 + e]) =
          *(const uint4*)(kp + ((size_t)bh * 2048 + t) * 64 + e);
    }
  }
  for (int c = tid; c < 320; c += 256) {
    int t = t0 + c;
    bool ok = (t >= 0 && t < 2048) && (pm[b * 2048 + t] != 0);
    sCM[c] = ok ? 0.0f : -3.0e38f;
  }
  __syncthreads();

  // Q A-frags from global (16B/lane, L2-hot)
  const __hip_bfloat16* qrow =
      qp + ((size_t)bh * 2048 + s0 + wave * 16 + cl) * 64 + ko;
  bf16x8 aq0 = *(const bf16x8*)(qrow);
  bf16x8 aq1 = *(const bf16x8*)(qrow + 32);

  // QK^T: 17 key tiles x 2 k-steps; B-frags from LDS
  f32x4 acc[17];
#pragma unroll
  for (int i = 0; i < 17; i++) {
    const int krow = (wave + i) * 16 + cl;
    bf16x8 b0 = *(const bf16x8*)(&sKP[krow * 72 + ko]);
    bf16x8 b1 = *(const bf16x8*)(&sKP[krow * 72 + ko + 32]);
    f32x4 z = {};
    z = __builtin_amdgcn_mfma_f32_16x16x32_bf16(aq0, b0, z, 0, 0, 0);
    acc[i] = __builtin_amdgcn_mfma_f32_16x16x32_bf16(aq1, b1, z, 0, 0, 0);
  }

  // mask + row max. Interior tiles: pm addend only (window holds structurally).
  float mrow[4] = {-3.0e38f, -3.0e38f, -3.0e38f, -3.0e38f};
#pragma unroll
  for (int i = 0; i < 17; i++) {
    const float ca = sCM[(wave + i) * 16 + cl];
#pragma unroll
    for (int r = 0; r < 4; r++) {
      float sv = acc[i][r] + ca;
      if (i == 0) {                      // dlt = cl - (g4+r) may be < 0
        if (cl < g4 + r) sv = -3.0e38f;
      } else if (i == 16) {              // dlt = 256 + cl - (g4+r) may be > 256
        if (cl > g4 + r) sv = -3.0e38f;
      }
      acc[i][r] = sv;
      mrow[r] = fmaxf(mrow[r], sv);
    }
  }
#pragma unroll
  for (int r = 0; r < 4; r++)
#pragma unroll
    for (int off = 1; off < 16; off <<= 1)
      mrow[r] = fmaxf(mrow[r], __shfl_xor(mrow[r], off));

  float lsum[4] = {0.f, 0.f, 0.f, 0.f};
#pragma unroll
  for (int i = 0; i < 17; i++)
#pragma unroll
    for (int r = 0; r < 4; r++) {
      float p = exp2f(acc[i][r] - mrow[r]);  // masked -> exact 0
      acc[i][r] = p;
      lsum[r] += p;
    }
#pragma unroll
  for (int r = 0; r < 4; r++)
#pragma unroll
    for (int off = 1; off < 16; off <<= 1)
      lsum[r] += __shfl_xor(lsum[r], off);

  __syncthreads();  // all waves done reading K -> safe to alias P over it

  // write P (bf16) into per-wave 16x328 strip (absolute col indexing)
  __hip_bfloat16* sp = sKP + wave * 5248;
#pragma unroll
  for (int i = 0; i < 17; i++) {
    const int c = (wave + i) * 16 + cl;
#pragma unroll
    for (int r = 0; r < 4; r++)
      sp[(g4 + r) * 328 + c] = __float2bfloat16(acc[i][r]);
  }
  {  // zero the one extra tile the 32-aligned PV k-steps touch
    const int zt = (wave & 1) ? (wave - 1) : (wave + 17);
    const int zc = zt * 16 + cl;
#pragma unroll
    for (int r = 0; r < 4; r++)
      sp[(g4 + r) * 328 + zc] = __float2bfloat16(0.f);
  }
  // no further barrier: each wave reads only its own strip

  // PV: 9 k-steps of 32 keys; V B-frags from VT3, fully dense
  f32x4 oacc[4] = {};
  const int k0 = wave >> 1;  // k-step base: abs keys [k0*32, k0*32+288)
  const __hip_bfloat16* vbase = vt + (size_t)bh * 131072;
#pragma unroll
  for (int ks = 0; ks < 9; ks++) {
    const int kk = (k0 + ks) * 32 + ko;   // abs key col, %8==0
    bf16x8 pa = *(const bf16x8*)(&sp[cl * 328 + kk]);
    int tv = t0 + kk; tv = min(max(tv, 0), 2040);  // tv%8==0
    const __hip_bfloat16* vrow = vbase + (tv >> 3) * 512;
#pragma unroll
    for (int ni = 0; ni < 4; ni++) {
      const int d = ni * 16 + cl;
      bf16x8 vb = *(const bf16x8*)(vrow + d * 8);
      oacc[ni] = __builtin_amdgcn_mfma_f32_16x16x32_bf16(pa, vb, oacc[ni], 0, 0, 0);
    }
  }

  // epilogue: /l, pm-zero, store vals[s][h*64+d]
#pragma unroll
  for (int r = 0; r < 4; r++) {
    float linv = 1.0f / fmaxf(lsum[r], 1e-20f);
    const int qr = wave * 16 + g4 + r;
    if (sCM[qr + 128] != 0.0f) linv = 0.0f;  // fully-masked query -> 0
    const size_t obase = ((size_t)(b * 2048 + s0 + qr)) * 512 + h * 64 + cl;
#pragma unroll
    for (int ni = 0; ni < 4; ni++)
      vals[obase + ni * 16] = __float2bfloat16(oacc[ni][r] * linv);
  }
}

// ---------------- output projection GEMM (64x128 tile, lds-dma, f32 out) ----
__global__ __launch_bounds__(256) void gemm_out(
    const __hip_bfloat16* __restrict__ A, const __hip_bfloat16* __restrict__ Bw,
    const float* __restrict__ bias, float* __restrict__ C) {
  __shared__ __hip_bfloat16 As[64 * 32];
  __shared__ __hip_bfloat16 Bs[128 * 32];

  const int tid = threadIdx.x, wave = tid >> 6, lane = tid & 63;
  const int m0 = blockIdx.x * 64, n0 = blockIdx.y * 128;
  const int wm = (wave >> 1) * 32, wn = (wave & 1) * 64;
  const int cl = lane & 15, ko = (lane >> 4) * 8;
  const int srow = wave * 16 + (lane >> 2);
  const int scol = (lane & 3) * 8;

  f32x4 acc[2][4] = {};

  for (int k0 = 0; k0 < 512; k0 += 32) {
    __syncthreads();
    ldsdma16(&As[wave * 512],        A  + (size_t)(m0 + srow) * 512 + k0 + scol);
    ldsdma16(&Bs[wave * 512],        Bw + (size_t)(n0 + srow) * 512 + k0 + scol);
    ldsdma16(&Bs[2048 + wave * 512], Bw + (size_t)(n0 + 64 + srow) * 512 + k0 + scol);
    __syncthreads();

    bf16x8 af[2], bf[4];
#pragma unroll
    for (int i = 0; i < 2; i++)
      af[i] = *(const bf16x8*)(&As[(wm + cl + i * 16) * 32 + ko]);
#pragma unroll
    for (int i = 0; i < 4; i++)
      bf[i] = *(const bf16x8*)(&Bs[(wn + cl + i * 16) * 32 + ko]);
#pragma unroll
    for (int mi = 0; mi < 2; mi++)
#pragma unroll
      for (int ni = 0; ni < 4; ni++)
        acc[mi][ni] = __builtin_amdgcn_mfma_f32_16x16x32_bf16(
            af[mi], bf[ni], acc[mi][ni], 0, 0, 0);
  }

  const int crow = (lane >> 4) * 4;
#pragma unroll
  for (int mi = 0; mi < 2; mi++) {
#pragma unroll
    for (int ni = 0; ni < 4; ni++) {
      const int n = n0 + wn + ni * 16 + cl;
      const float bv = bias[n];
      const int mb = m0 + wm + mi * 16 + crow;
#pragma unroll
      for (int r = 0; r < 4; r++)
        C[(size_t)(mb + r) * 512 + n] = acc[mi][ni][r] + bv;
    }
  }
}

extern "C" void kernel_launch(void* const* d_in, const int* in_sizes, int n_in,
                              void* d_out, int out_size, void* d_ws, size_t ws_size,
                              hipStream_t stream) {
  const float* x     = (const float*)d_in[0];   // (2,2048,512)
  const int*   pm    = (const int*)d_in[1];     // (2,2048)
  const float* qkv_w = (const float*)d_in[2];   // (1536,512)
  const float* qkv_b = (const float*)d_in[3];   // (1536,)
  const float* o_w   = (const float*)d_in[4];   // (512,512)
  const float* o_b   = (const float*)d_in[5];   // (512,)
  float* out = (float*)d_out;                   // (2,2048,512)

  __hip_bfloat16* wsb   = (__hip_bfloat16*)d_ws;
  __hip_bfloat16* xb    = wsb;               // 2097152
  __hip_bfloat16* wqkvb = wsb + 2097152;     // 786432
  __hip_bfloat16* wob   = wsb + 2883584;     // 262144
  __hip_bfloat16* qp    = wsb + 3145728;     // 2097152  [bh][s][64] (scaled)
  __hip_bfloat16* kp    = wsb + 5242880;     // 2097152  [bh][s][64]
  __hip_bfloat16* vt    = wsb + 7340032;     // 2097152  VT3[bh][k/8][d][k%8]
  __hip_bfloat16* vals  = wsb + 9437184;     // 2097152  [s][512]

  dim3 blk(256);
  cvt3_kernel<<<dim3(3072), blk, 0, stream>>>(
      x, (unsigned short*)xb, 2097152,
      qkv_w, (unsigned short*)wqkvb, 786432,
      o_w, (unsigned short*)wob, 262144);
  gemm_qkv<<<dim3(32, 12), blk, 0, stream>>>(
      xb, wqkvb, qkv_b, qp, kp, (unsigned short*)vt);
  attn_mfma<<<dim3(512), blk, 0, stream>>>(qp, kp, vt, pm, vals);
  gemm_out<<<dim3(64, 4), blk, 0, stream>>>(vals, wob, o_b, out);
}